// Round 8
// baseline (273.661 us; speedup 1.0000x reference)
//
#include <hip/hip_runtime.h>

// VectorQuantizer on MI355X (gfx950) — round 10: 2-pass fp16 split (r9 + compile fix)
// x: [262144, 64] fp32; embeddings: [64, 512] fp32 (codes are COLUMNS)
// out: quantized [N*64] fp32 ++ loss scalar
//
// sim = x.eh where x = xh + xl (fp16 split, x captured to ~2^-22) and
// eh = fp16(e) (the ONLY approximation: e's fp16 rounding, sim err RMS ~9e-4).
// score = sim - 0.5*||e||^2 (acc-initialized); argmax == argmin dist.
// Near-tie gap < TIE_TH=0.02 (7.7 sigma of the fp16-e error) -> exact fp64
// rescan (expected ~1.2% of rows).
//
// r10 = r9 with the cvt_pkrtz type error fixed: plain scalar (_Float16) RNE
// casts in the prologue (hi = RNE16(f), lo = RNE16(f - hi)); same 2^-22 split.
//
// Why vs round-8 (112us main, all pipes <30%, 16 waves/CU): 6 structural
// variants proved the table path isn't the lever; the 3-pass bf16 algorithm
// taxed every pipe. 2-pass fp16: MFMA 3.15M->2.1M, ds_read/t 4->2, el table
// DELETED -> LDS 130->66KB -> 2 blocks/CU = 32 waves/CU, and the ~60-reg live
// set fits the 64-reg allocation the compiler insists on for this shape.
// Keeps r7/r8 overhead trims: merged prep, final fused via done-counter.

#define NVEC 262144
#define DDIM 64
#define KCB  512
#define TIE_TH 0.02f

// ws layout (4-byte units)
#define WS_LOSS  0
#define WS_DONE  1                       // done-block counter (uint)
#define WS_CNORM 64                      // 512 floats
#define WS_ET    1024                    // 512*64 floats (code-major codebook)
#define WS_EH    (WS_ET + KCB * DDIM)    // 32 tiles * 2 chunks * 64 lanes * 16B
#define WS_EL    (WS_EH + 32 * 2 * 64 * 4)   // (unused in fp16 scheme)
#define WS_END   (WS_EL + 32 * 2 * 64 * 4)

typedef __attribute__((ext_vector_type(8))) _Float16 f16x8;
typedef __attribute__((ext_vector_type(4))) float f32x4;

// ---------------- merged prep: et, cnorm, eh fragments, zero loss+counter ----------------
// grid 8 x 512. tid 0..4095.
__global__ __launch_bounds__(512) void vq_prep(const float* __restrict__ emb,
                                               float* __restrict__ wsf) {
    const int tid = blockIdx.x * 512 + threadIdx.x;   // 0..4095

    // ---- part B: et (code-major) + cnorm (exact fp32), 8 threads per code ----
    {
        int k  = tid >> 3;            // 0..511
        int d0 = (tid & 7) * 8;
        float s = 0.f;
        float* et = wsf + WS_ET;
        #pragma unroll
        for (int i = 0; i < 8; ++i) {
            float e = emb[(d0 + i) * KCB + k];
            s += e * e;
            et[k * DDIM + d0 + i] = e;
        }
        s += __shfl_xor(s, 1);
        s += __shfl_xor(s, 2);
        s += __shfl_xor(s, 4);
        if ((tid & 7) == 0) wsf[WS_CNORM + k] = s;
        if (tid == 0) {
            wsf[WS_LOSS] = 0.f;
            ((unsigned*)wsf)[WS_DONE] = 0u;
        }
    }

    // ---- part A: codebook MFMA A-fragments (fp16, RNE) ----
    // frag index ((t*2+c)*64 + lane): 8 f16 = A[m=t*16+(lane&15)][k=c*32+quad*8+j]
    {
        int l = tid & 63;
        int c = (tid >> 6) & 1;
        int t = tid >> 7;
        int m = t * 16 + (l & 15);
        int dbase = c * 32 + ((l >> 4) & 3) * 8;
        unsigned hh[4];
        #pragma unroll
        for (int j2 = 0; j2 < 4; ++j2) {
            float f0 = emb[(dbase + 2 * j2 + 0) * KCB + m];
            float f1 = emb[(dbase + 2 * j2 + 1) * KCB + m];
            union { _Float16 h; unsigned short u; } a, b;
            a.h = (_Float16)f0;           // RNE
            b.h = (_Float16)f1;
            hh[j2] = (unsigned)a.u | ((unsigned)b.u << 16);
        }
        uint4* ehp = (uint4*)(wsf + WS_EH);
        ehp[tid] = make_uint4(hh[0], hh[1], hh[2], hh[3]);
    }
}

// ---------------- main: 1024-thr block = 16 waves, eh table in LDS ----------------
// Grid 512: each block owns 512 rows (wave: 32 rows, j=2). LDS 66KB ->
// 2 blocks/CU = 32 waves/CU (2x round-8's occupancy). 64-reg allocation is
// now sufficient (~60-reg live set): no spill, prefetch survives.
__global__ __launch_bounds__(1024) void vq_main_mfma(const float* __restrict__ x,
                                                     float* __restrict__ wsf,
                                                     float* __restrict__ out) {
    const int lane = threadIdx.x & 63;
    const int quad = lane >> 4;
    const int wid  = threadIdx.x >> 6;
    const int nbase = blockIdx.x * 512 + wid * 32;

    __shared__ uint4  sh_eh[32 * 2 * 64];   // 64 KB
    __shared__ float4 sh_cn[128];           // 2 KB: -0.5 * ||e||^2
    __shared__ float  redls[16];

    // ---- stage eh fragments + scaled norms into LDS (once per block) ----
    {
        const uint4* geh = (const uint4*)(wsf + WS_EH);
        const int tid = threadIdx.x;
        #pragma unroll
        for (int i = 0; i < 4; ++i)
            sh_eh[tid + i * 1024] = geh[tid + i * 1024];
        if (tid < 128) {
            float4 c = ((const float4*)(wsf + WS_CNORM))[tid];
            sh_cn[tid] = make_float4(-0.5f * c.x, -0.5f * c.y,
                                     -0.5f * c.z, -0.5f * c.w);
        }
    }

    const float* __restrict__ et = wsf + WS_ET;
    float* __restrict__ loss_accum = wsf + WS_LOSS;

    // ---- load 32 x rows, build fp16 hi/lo B-fragments, accumulate ||x||^2 ----
    // (overlaps the LDS staging; barrier after)
    f16x8 xh[2][2], xl[2][2];
    float xnorm[2];
    #pragma unroll
    for (int j = 0; j < 2; ++j) {
        float s = 0.f;
        #pragma unroll
        for (int c = 0; c < 2; ++c) {
            const float* xrow = x + (size_t)(nbase + j * 16 + (lane & 15)) * DDIM
                                  + c * 32 + quad * 8;
            float4 xa = *(const float4*)xrow;
            float4 xb = *(const float4*)(xrow + 4);
            s += xa.x * xa.x + xa.y * xa.y + xa.z * xa.z + xa.w * xa.w;
            s += xb.x * xb.x + xb.y * xb.y + xb.z * xb.z + xb.w * xb.w;
            float f[8] = {xa.x, xa.y, xa.z, xa.w, xb.x, xb.y, xb.z, xb.w};
            union { f16x8 v; _Float16 h[8]; } H, L;
            #pragma unroll
            for (int e = 0; e < 8; ++e) {
                _Float16 hh = (_Float16)f[e];            // RNE hi split
                H.h[e] = hh;
                L.h[e] = (_Float16)(f[e] - (float)hh);   // residual
            }
            xh[j][c] = H.v;
            xl[j][c] = L.v;
        }
        // sum partial ||x||^2 across the 4 quads (bits 4,5 of lane)
        s += __shfl_xor(s, 16);
        s += __shfl_xor(s, 32);
        xnorm[j] = s;
    }

    __syncthreads();

    const f16x8* __restrict__ ehv = (const f16x8*)sh_eh;

    // ---- argmax of score = x.eh - 0.5*||e||^2 over 32 code-tiles ----
    float best[2], second[2];
    int bestv[2];  // t*16 + reg  (full code = bestv + quad*4)
    #pragma unroll
    for (int j = 0; j < 2; ++j) { best[j] = -3.4e38f; second[j] = -3.4e38f; bestv[j] = 0; }

    // prefetched eh fragments for tile t (1-deep)
    f16x8 eh0 = ehv[lane], eh1 = ehv[64 + lane];

    #pragma unroll 1
    for (int t = 0; t < 32; ++t) {
        const int tn = (t + 1) & 31;
        f16x8 neh0 = ehv[(tn * 2 + 0) * 64 + lane];
        f16x8 neh1 = ehv[(tn * 2 + 1) * 64 + lane];
        float4 cn = sh_cn[t * 4 + quad];
        const int kb = t * 16;
        #pragma unroll
        for (int j = 0; j < 2; ++j) {
            f32x4 acc = {cn.x, cn.y, cn.z, cn.w};   // start at -0.5*||e||^2
            acc = __builtin_amdgcn_mfma_f32_16x16x32_f16(eh0, xh[j][0], acc, 0, 0, 0);
            acc = __builtin_amdgcn_mfma_f32_16x16x32_f16(eh1, xh[j][1], acc, 0, 0, 0);
            acc = __builtin_amdgcn_mfma_f32_16x16x32_f16(eh0, xl[j][0], acc, 0, 0, 0);
            acc = __builtin_amdgcn_mfma_f32_16x16x32_f16(eh1, xl[j][1], acc, 0, 0, 0);
            #pragma unroll
            for (int r = 0; r < 4; ++r) {
                float s = acc[r];
                // new second = median(s, best, second) given best >= second
                second[j] = __builtin_amdgcn_fmed3f(s, best[j], second[j]);
                bool gt = s > best[j];
                bestv[j] = gt ? (kb + r) : bestv[j];
                best[j] = fmaxf(best[j], s);
            }
        }
        eh0 = neh0; eh1 = neh1;
    }

    // ---- reduce across the 4 quads (lanes n, n+16, n+32, n+48) ----
    int bk[2];
    #pragma unroll
    for (int j = 0; j < 2; ++j) bk[j] = bestv[j] + quad * 4;
    #pragma unroll
    for (int j = 0; j < 2; ++j) {
        #pragma unroll
        for (int m = 16; m <= 32; m <<= 1) {
            float ob = __shfl_xor(best[j], m);
            float os = __shfl_xor(second[j], m);
            int   ok = __shfl_xor(bk[j], m);
            float nb = fmaxf(best[j], ob);
            float ns = fmaxf(fmaxf(second[j], os), fminf(best[j], ob));
            bool take = (ob > best[j]) || (ob == best[j] && ok < bk[j]);
            bk[j] = take ? ok : bk[j];
            best[j] = nb;
            second[j] = ns;
        }
    }

    // ---- back to distance domain: dist = -2*score  (||x||^2 dropped) ----
    float bd[2], sd[2];
    #pragma unroll
    for (int j = 0; j < 2; ++j) { bd[j] = -2.f * best[j]; sd[j] = -2.f * second[j]; }

    // ---- near-tie: whole-wave cooperative exact fp64 rescan (~1.2% of rows) ----
    #pragma unroll
    for (int j = 0; j < 2; ++j) {
        unsigned long long need = __ballot(sd[j] - bd[j] < TIE_TH) & 0xFFFFULL;
        while (need) {
            int nl = __ffsll(need) - 1;
            need &= need - 1;
            const float* xr = x + (size_t)(nbase + j * 16 + nl) * DDIM;
            double dmin = 1e300;
            int kmin = 0;
            #pragma unroll
            for (int i = 0; i < 8; ++i) {
                int k = lane * 8 + i;
                const float* er = et + k * DDIM;
                double s = 0.0;
                for (int d4 = 0; d4 < 16; ++d4) {
                    float4 xv = *(const float4*)(xr + d4 * 4);
                    float4 ev = *(const float4*)(er + d4 * 4);
                    double a = (double)xv.x - (double)ev.x; s += a * a;
                    double b = (double)xv.y - (double)ev.y; s += b * b;
                    double c = (double)xv.z - (double)ev.z; s += c * c;
                    double e = (double)xv.w - (double)ev.w; s += e * e;
                }
                if (s < dmin) { dmin = s; kmin = k; }
            }
            #pragma unroll
            for (int m = 1; m < 64; m <<= 1) {
                double od = __shfl_xor(dmin, m);
                int   ok = __shfl_xor(kmin, m);
                if (od < dmin || (od == dmin && ok < kmin)) { dmin = od; kmin = ok; }
            }
            if ((lane & 15) == nl) {
                bk[j] = kmin;
                bd[j] = (float)dmin - xnorm[j];  // keep loss exact
            }
        }
    }

    // ---- loss partial: sum (q-x)^2 = xnorm + bd over this wave's 32 n ----
    float ls = 0.f;
    if (lane < 16) {
        #pragma unroll
        for (int j = 0; j < 2; ++j) ls += fmaxf(xnorm[j] + bd[j], 0.f);
    }
    #pragma unroll
    for (int m = 1; m < 64; m <<= 1) ls += __shfl_xor(ls, m);

    // ---- write quantized rows: lane -> (n = lane>>2, 64B slice = lane&3) ----
    #pragma unroll
    for (int j = 0; j < 2; ++j) {
        int bkn = __shfl(bk[j], lane >> 2);
        const float4* er = (const float4*)(et + (size_t)bkn * DDIM + (lane & 3) * 16);
        float4* op = (float4*)(out + (size_t)(nbase + j * 16 + (lane >> 2)) * DDIM
                                   + (lane & 3) * 16);
        op[0] = er[0]; op[1] = er[1]; op[2] = er[2]; op[3] = er[3];
    }

    // ---- fused final: block loss reduce + done-counter, last block writes ----
    if (lane == 0) redls[wid] = ls;
    __syncthreads();
    if (threadIdx.x == 0) {
        float Lb = 0.f;
        #pragma unroll
        for (int i = 0; i < 16; ++i) Lb += redls[i];
        atomicAdd(loss_accum, Lb);
        __threadfence();
        unsigned d = atomicAdd((unsigned*)wsf + WS_DONE, 1u);
        if (d == gridDim.x - 1) {
            float L = atomicAdd(loss_accum, 0.f);   // coherent read-back
            out[(size_t)NVEC * DDIM] = 1.25f * L / 16777216.f;
        }
    }
}

// ---------------- legacy fallback path (ws too small for fragment tables) ----------------
__global__ __launch_bounds__(512) void vq_prep1(const float* __restrict__ emb,
                                                float* __restrict__ wsf) {
    int k = threadIdx.x;
    float s = 0.f;
    float* et = wsf + WS_ET;
    #pragma unroll
    for (int d = 0; d < DDIM; ++d) {
        float e = emb[d * KCB + k];
        s += e * e;
        et[k * DDIM + d] = e;
    }
    wsf[WS_CNORM + k] = s;
    if (k == 0) wsf[WS_LOSS] = 0.f;
}

__global__ __launch_bounds__(256) void vq_main_legacy(const float* __restrict__ x,
                                                      const float* __restrict__ emb,
                                                      const float* __restrict__ wsf,
                                                      float* __restrict__ out,
                                                      float* __restrict__ loss_accum) {
    const int n = blockIdx.x * 256 + threadIdx.x;
    const float* __restrict__ cnorm = wsf + WS_CNORM;
    const float* __restrict__ et    = wsf + WS_ET;
    float xr[DDIM];
    {
        const float4* xp = (const float4*)(x + (size_t)n * DDIM);
        #pragma unroll
        for (int d4 = 0; d4 < DDIM / 4; ++d4) {
            float4 v = xp[d4];
            xr[4 * d4 + 0] = v.x; xr[4 * d4 + 1] = v.y;
            xr[4 * d4 + 2] = v.z; xr[4 * d4 + 3] = v.w;
        }
    }
    float best = 3.4e38f, second = 3.4e38f;
    int bestk = 0;
    for (int k0 = 0; k0 < KCB; k0 += 8) {
        float acc[8];
        #pragma unroll
        for (int j = 0; j < 8; ++j) {
            const float* ek = et + (k0 + j) * DDIM;
            float s = 0.f;
            #pragma unroll
            for (int d = 0; d < DDIM; ++d) s += xr[d] * ek[d];
            acc[j] = s;
        }
        #pragma unroll
        for (int j = 0; j < 8; ++j) {
            float dist = cnorm[k0 + j] - 2.f * acc[j];
            if (dist < best) { second = best; best = dist; bestk = k0 + j; }
            else if (dist < second) { second = dist; }
        }
    }
    if (second - best < TIE_TH) {
        double bestd = 1e300;
        int bkk = 0;
        for (int k = 0; k < KCB; ++k) {
            const float* ek = et + k * DDIM;
            double s = 0.0;
            #pragma unroll
            for (int d = 0; d < DDIM; ++d) {
                double diff = (double)xr[d] - (double)ek[d];
                s += diff * diff;
            }
            if (s < bestd) { bestd = s; bkk = k; }
        }
        bestk = bkk;
    }
    float sq = 0.f;
    {
        const float4* qp = (const float4*)(et + bestk * DDIM);
        float4* op = (float4*)(out + (size_t)n * DDIM);
        #pragma unroll
        for (int d4 = 0; d4 < DDIM / 4; ++d4) {
            float4 q = qp[d4];
            op[d4] = q;
            float a = q.x - xr[4 * d4 + 0];
            float b = q.y - xr[4 * d4 + 1];
            float c = q.z - xr[4 * d4 + 2];
            float e = q.w - xr[4 * d4 + 3];
            sq += a * a + b * b + c * c + e * e;
        }
    }
    #pragma unroll
    for (int off = 32; off > 0; off >>= 1) sq += __shfl_down(sq, off);
    __shared__ float red[4];
    const int lane = threadIdx.x & 63;
    const int wid  = threadIdx.x >> 6;
    if (lane == 0) red[wid] = sq;
    __syncthreads();
    if (threadIdx.x == 0) atomicAdd(loss_accum, red[0] + red[1] + red[2] + red[3]);
}

__global__ void vq_final(const float* __restrict__ loss_accum,
                         float* __restrict__ out) {
    out[(size_t)NVEC * DDIM] = 1.25f * loss_accum[0] / 16777216.f;
}

extern "C" void kernel_launch(void* const* d_in, const int* in_sizes, int n_in,
                              void* d_out, int out_size, void* d_ws, size_t ws_size,
                              hipStream_t stream) {
    const float* x   = (const float*)d_in[0];
    const float* emb = (const float*)d_in[1];
    float* out = (float*)d_out;
    float* wsf = (float*)d_ws;

    if (ws_size >= (size_t)WS_END * 4) {
        vq_prep<<<8, 512, 0, stream>>>(emb, wsf);
        vq_main_mfma<<<NVEC / 512, 1024, 0, stream>>>(x, wsf, out);
        // loss written by last finishing block of vq_main_mfma
    } else {
        vq_prep1<<<1, 512, 0, stream>>>(emb, wsf);
        vq_main_legacy<<<NVEC / 256, 256, 0, stream>>>(x, emb, wsf, out, wsf + WS_LOSS);
        vq_final<<<1, 1, 0, stream>>>(wsf + WS_LOSS, out);
    }
}

// Round 9
// 248.277 us; speedup vs baseline: 1.1022x; 1.1022x over previous
//
#include <hip/hip_runtime.h>

// VectorQuantizer on MI355X (gfx950) — round 11: fp16 2-pass, r8 geometry, 64-reg diet
// x: [262144, 64] fp32; embeddings: [64, 512] fp32 (codes are COLUMNS)
// out: quantized [N*64] fp32 ++ loss scalar
//
// sim = x.eh where x = xh + xl (fp16 RNE split, x captured to ~2^-22) and
// eh = fp16(e) (only approximation; sim err RMS ~1e-3). score = sim-0.5||e||^2
// (acc-initialized); argmax == argmin dist. Near-tie gap < TIE_TH=0.02 ->
// exact fp64 rescan (~1.3% of rows; VERIFIED passing in r10, absmax 0.00195).
//
// r11 vs r10 (194us): r10's live set (~70: 32 x-frags + 16 prefetch + 8 acc +
// scoreboard) overflowed the 60-reg allocation -> t-loop scratch reloads
// (~1800cyc/tile; MfmaUtil 7%). And the 2-blocks/CU bet failed (occupancy
// 29.6% == r8), making the halved grid two serial prologue rounds.
// Fix: r8's geometry (grid 256, 2 passes/block = best measured, 112us) and
// DELETE the eh prefetch regs -> live set ~62 <= 64 (the allocation this
// shape always gets: r3/r5/r8 all 64). 16 waves/CU TLP hides the ds_read
// latency the prefetch was covering. Barrier hoisted: once after staging.
// Keeps r7/r8 overhead trims (merged prep, fused final via done-counter).

#define NVEC 262144
#define DDIM 64
#define KCB  512
#define TIE_TH 0.02f

// ws layout (4-byte units)
#define WS_LOSS  0
#define WS_DONE  1                       // done-block counter (uint)
#define WS_CNORM 64                      // 512 floats
#define WS_ET    1024                    // 512*64 floats (code-major codebook)
#define WS_EH    (WS_ET + KCB * DDIM)    // 32 tiles * 2 chunks * 64 lanes * 16B
#define WS_EL    (WS_EH + 32 * 2 * 64 * 4)   // (unused in fp16 scheme)
#define WS_END   (WS_EL + 32 * 2 * 64 * 4)

typedef __attribute__((ext_vector_type(8))) _Float16 f16x8;
typedef __attribute__((ext_vector_type(4))) float f32x4;

// ---------------- merged prep: et, cnorm, eh fragments, zero loss+counter ----------------
// grid 8 x 512. tid 0..4095.
__global__ __launch_bounds__(512) void vq_prep(const float* __restrict__ emb,
                                               float* __restrict__ wsf) {
    const int tid = blockIdx.x * 512 + threadIdx.x;   // 0..4095

    // ---- part B: et (code-major) + cnorm (exact fp32), 8 threads per code ----
    {
        int k  = tid >> 3;            // 0..511
        int d0 = (tid & 7) * 8;
        float s = 0.f;
        float* et = wsf + WS_ET;
        #pragma unroll
        for (int i = 0; i < 8; ++i) {
            float e = emb[(d0 + i) * KCB + k];
            s += e * e;
            et[k * DDIM + d0 + i] = e;
        }
        s += __shfl_xor(s, 1);
        s += __shfl_xor(s, 2);
        s += __shfl_xor(s, 4);
        if ((tid & 7) == 0) wsf[WS_CNORM + k] = s;
        if (tid == 0) {
            wsf[WS_LOSS] = 0.f;
            ((unsigned*)wsf)[WS_DONE] = 0u;
        }
    }

    // ---- part A: codebook MFMA A-fragments (fp16, RNE) ----
    // frag index ((t*2+c)*64 + lane): 8 f16 = A[m=t*16+(lane&15)][k=c*32+quad*8+j]
    {
        int l = tid & 63;
        int c = (tid >> 6) & 1;
        int t = tid >> 7;
        int m = t * 16 + (l & 15);
        int dbase = c * 32 + ((l >> 4) & 3) * 8;
        unsigned hh[4];
        #pragma unroll
        for (int j2 = 0; j2 < 4; ++j2) {
            float f0 = emb[(dbase + 2 * j2 + 0) * KCB + m];
            float f1 = emb[(dbase + 2 * j2 + 1) * KCB + m];
            union { _Float16 h; unsigned short u; } a, b;
            a.h = (_Float16)f0;           // RNE
            b.h = (_Float16)f1;
            hh[j2] = (unsigned)a.u | ((unsigned)b.u << 16);
        }
        uint4* ehp = (uint4*)(wsf + WS_EH);
        ehp[tid] = make_uint4(hh[0], hh[1], hh[2], hh[3]);
    }
}

// ---------------- main: grid 256, 1024-thr block = 16 waves, 2 passes ----------------
// LDS: eh 64KB + cn 2KB. Each wave: 32 rows/pass (j=2). No prefetch regs:
// live set ~62 fits the 64-reg allocation; 16 waves/CU TLP hides ds_read.
__global__ __launch_bounds__(1024) void vq_main_mfma(const float* __restrict__ x,
                                                     float* __restrict__ wsf,
                                                     float* __restrict__ out) {
    const int lane = threadIdx.x & 63;
    const int quad = lane >> 4;
    const int wid  = threadIdx.x >> 6;

    __shared__ uint4  sh_eh[32 * 2 * 64];   // 64 KB
    __shared__ float4 sh_cn[128];           // 2 KB: -0.5 * ||e||^2
    __shared__ float  redls[16];

    // ---- stage eh fragments + scaled norms into LDS (once per block) ----
    {
        const uint4* geh = (const uint4*)(wsf + WS_EH);
        const int tid = threadIdx.x;
        #pragma unroll
        for (int i = 0; i < 4; ++i)
            sh_eh[tid + i * 1024] = geh[tid + i * 1024];
        if (tid < 128) {
            float4 c = ((const float4*)(wsf + WS_CNORM))[tid];
            sh_cn[tid] = make_float4(-0.5f * c.x, -0.5f * c.y,
                                     -0.5f * c.z, -0.5f * c.w);
        }
    }

    const float* __restrict__ et = wsf + WS_ET;
    float* __restrict__ loss_accum = wsf + WS_LOSS;
    const f16x8* __restrict__ ehv = (const f16x8*)sh_eh;

    float loss_ws = 0.f;

    #pragma unroll 1
    for (int pass = 0; pass < 2; ++pass) {
        const int nbase = (blockIdx.x * 2 + pass) * 512 + wid * 32;

        // ---- load 32 x rows, build fp16 hi/lo B-fragments, ||x||^2 ----
        f16x8 xh[2][2], xl[2][2];
        float xnorm[2];
        #pragma unroll
        for (int j = 0; j < 2; ++j) {
            float s = 0.f;
            #pragma unroll
            for (int c = 0; c < 2; ++c) {
                const float* xrow = x + (size_t)(nbase + j * 16 + (lane & 15)) * DDIM
                                      + c * 32 + quad * 8;
                float4 xa = *(const float4*)xrow;
                float4 xb = *(const float4*)(xrow + 4);
                s += xa.x * xa.x + xa.y * xa.y + xa.z * xa.z + xa.w * xa.w;
                s += xb.x * xb.x + xb.y * xb.y + xb.z * xb.z + xb.w * xb.w;
                float f[8] = {xa.x, xa.y, xa.z, xa.w, xb.x, xb.y, xb.z, xb.w};
                union { f16x8 v; _Float16 h[8]; } H, L;
                #pragma unroll
                for (int e = 0; e < 8; ++e) {
                    _Float16 hh = (_Float16)f[e];            // RNE hi split
                    H.h[e] = hh;
                    L.h[e] = (_Float16)(f[e] - (float)hh);   // residual
                }
                xh[j][c] = H.v;
                xl[j][c] = L.v;
            }
            // sum partial ||x||^2 across the 4 quads (bits 4,5 of lane)
            s += __shfl_xor(s, 16);
            s += __shfl_xor(s, 32);
            xnorm[j] = s;
        }

        if (pass == 0) __syncthreads();   // staging visible before first t-loop

        // ---- argmax of score = x.eh - 0.5*||e||^2 over 32 code-tiles ----
        float best[2], second[2];
        int bestv[2];  // t*16 + reg  (full code = bestv + quad*4)
        #pragma unroll
        for (int j = 0; j < 2; ++j) { best[j] = -3.4e38f; second[j] = -3.4e38f; bestv[j] = 0; }

        #pragma unroll 1
        for (int t = 0; t < 32; ++t) {
            f16x8 eh0 = ehv[(t * 2 + 0) * 64 + lane];
            f16x8 eh1 = ehv[(t * 2 + 1) * 64 + lane];
            float4 cn = sh_cn[t * 4 + quad];
            const int kb = t * 16;
            #pragma unroll
            for (int j = 0; j < 2; ++j) {
                f32x4 acc = {cn.x, cn.y, cn.z, cn.w};   // start at -0.5*||e||^2
                acc = __builtin_amdgcn_mfma_f32_16x16x32_f16(eh0, xh[j][0], acc, 0, 0, 0);
                acc = __builtin_amdgcn_mfma_f32_16x16x32_f16(eh1, xh[j][1], acc, 0, 0, 0);
                acc = __builtin_amdgcn_mfma_f32_16x16x32_f16(eh0, xl[j][0], acc, 0, 0, 0);
                acc = __builtin_amdgcn_mfma_f32_16x16x32_f16(eh1, xl[j][1], acc, 0, 0, 0);
                #pragma unroll
                for (int r = 0; r < 4; ++r) {
                    float s = acc[r];
                    // new second = median(s, best, second) given best >= second
                    second[j] = __builtin_amdgcn_fmed3f(s, best[j], second[j]);
                    bool gt = s > best[j];
                    bestv[j] = gt ? (kb + r) : bestv[j];
                    best[j] = fmaxf(best[j], s);
                }
            }
        }

        // ---- reduce across the 4 quads (lanes n, n+16, n+32, n+48) ----
        int bk[2];
        #pragma unroll
        for (int j = 0; j < 2; ++j) bk[j] = bestv[j] + quad * 4;
        #pragma unroll
        for (int j = 0; j < 2; ++j) {
            #pragma unroll
            for (int m = 16; m <= 32; m <<= 1) {
                float ob = __shfl_xor(best[j], m);
                float os = __shfl_xor(second[j], m);
                int   ok = __shfl_xor(bk[j], m);
                float nb = fmaxf(best[j], ob);
                float ns = fmaxf(fmaxf(second[j], os), fminf(best[j], ob));
                bool take = (ob > best[j]) || (ob == best[j] && ok < bk[j]);
                bk[j] = take ? ok : bk[j];
                best[j] = nb;
                second[j] = ns;
            }
        }

        // ---- back to distance domain: dist = -2*score  (||x||^2 dropped) ----
        float bd[2], sd[2];
        #pragma unroll
        for (int j = 0; j < 2; ++j) { bd[j] = -2.f * best[j]; sd[j] = -2.f * second[j]; }

        // ---- near-tie: whole-wave cooperative exact fp64 rescan (~1.3%) ----
        #pragma unroll
        for (int j = 0; j < 2; ++j) {
            unsigned long long need = __ballot(sd[j] - bd[j] < TIE_TH) & 0xFFFFULL;
            while (need) {
                int nl = __ffsll(need) - 1;
                need &= need - 1;
                const float* xr = x + (size_t)(nbase + j * 16 + nl) * DDIM;
                double dmin = 1e300;
                int kmin = 0;
                #pragma unroll
                for (int i = 0; i < 8; ++i) {
                    int k = lane * 8 + i;
                    const float* er = et + k * DDIM;
                    double s = 0.0;
                    for (int d4 = 0; d4 < 16; ++d4) {
                        float4 xv = *(const float4*)(xr + d4 * 4);
                        float4 ev = *(const float4*)(er + d4 * 4);
                        double a = (double)xv.x - (double)ev.x; s += a * a;
                        double b = (double)xv.y - (double)ev.y; s += b * b;
                        double c = (double)xv.z - (double)ev.z; s += c * c;
                        double e = (double)xv.w - (double)ev.w; s += e * e;
                    }
                    if (s < dmin) { dmin = s; kmin = k; }
                }
                #pragma unroll
                for (int m = 1; m < 64; m <<= 1) {
                    double od = __shfl_xor(dmin, m);
                    int   ok = __shfl_xor(kmin, m);
                    if (od < dmin || (od == dmin && ok < kmin)) { dmin = od; kmin = ok; }
                }
                if ((lane & 15) == nl) {
                    bk[j] = kmin;
                    bd[j] = (float)dmin - xnorm[j];  // keep loss exact
                }
            }
        }

        // ---- loss partial: sum (q-x)^2 = xnorm + bd over this wave's 32 n ----
        float ls = 0.f;
        if (lane < 16) {
            #pragma unroll
            for (int j = 0; j < 2; ++j) ls += fmaxf(xnorm[j] + bd[j], 0.f);
        }
        #pragma unroll
        for (int m = 1; m < 64; m <<= 1) ls += __shfl_xor(ls, m);
        loss_ws += ls;

        // ---- write quantized rows: lane -> (n = lane>>2, 64B slice = lane&3) ----
        #pragma unroll
        for (int j = 0; j < 2; ++j) {
            int bkn = __shfl(bk[j], lane >> 2);
            const float4* er = (const float4*)(et + (size_t)bkn * DDIM + (lane & 3) * 16);
            float4* op = (float4*)(out + (size_t)(nbase + j * 16 + (lane >> 2)) * DDIM
                                       + (lane & 3) * 16);
            op[0] = er[0]; op[1] = er[1]; op[2] = er[2]; op[3] = er[3];
        }
    }

    // ---- fused final: block loss reduce + done-counter, last block writes ----
    if (lane == 0) redls[wid] = loss_ws;
    __syncthreads();
    if (threadIdx.x == 0) {
        float Lb = 0.f;
        #pragma unroll
        for (int i = 0; i < 16; ++i) Lb += redls[i];
        atomicAdd(loss_accum, Lb);
        __threadfence();
        unsigned d = atomicAdd((unsigned*)wsf + WS_DONE, 1u);
        if (d == gridDim.x - 1) {
            float L = atomicAdd(loss_accum, 0.f);   // coherent read-back
            out[(size_t)NVEC * DDIM] = 1.25f * L / 16777216.f;
        }
    }
}

// ---------------- legacy fallback path (ws too small for fragment tables) ----------------
__global__ __launch_bounds__(512) void vq_prep1(const float* __restrict__ emb,
                                                float* __restrict__ wsf) {
    int k = threadIdx.x;
    float s = 0.f;
    float* et = wsf + WS_ET;
    #pragma unroll
    for (int d = 0; d < DDIM; ++d) {
        float e = emb[d * KCB + k];
        s += e * e;
        et[k * DDIM + d] = e;
    }
    wsf[WS_CNORM + k] = s;
    if (k == 0) wsf[WS_LOSS] = 0.f;
}

__global__ __launch_bounds__(256) void vq_main_legacy(const float* __restrict__ x,
                                                      const float* __restrict__ emb,
                                                      const float* __restrict__ wsf,
                                                      float* __restrict__ out,
                                                      float* __restrict__ loss_accum) {
    const int n = blockIdx.x * 256 + threadIdx.x;
    const float* __restrict__ cnorm = wsf + WS_CNORM;
    const float* __restrict__ et    = wsf + WS_ET;
    float xr[DDIM];
    {
        const float4* xp = (const float4*)(x + (size_t)n * DDIM);
        #pragma unroll
        for (int d4 = 0; d4 < DDIM / 4; ++d4) {
            float4 v = xp[d4];
            xr[4 * d4 + 0] = v.x; xr[4 * d4 + 1] = v.y;
            xr[4 * d4 + 2] = v.z; xr[4 * d4 + 3] = v.w;
        }
    }
    float best = 3.4e38f, second = 3.4e38f;
    int bestk = 0;
    for (int k0 = 0; k0 < KCB; k0 += 8) {
        float acc[8];
        #pragma unroll
        for (int j = 0; j < 8; ++j) {
            const float* ek = et + (k0 + j) * DDIM;
            float s = 0.f;
            #pragma unroll
            for (int d = 0; d < DDIM; ++d) s += xr[d] * ek[d];
            acc[j] = s;
        }
        #pragma unroll
        for (int j = 0; j < 8; ++j) {
            float dist = cnorm[k0 + j] - 2.f * acc[j];
            if (dist < best) { second = best; best = dist; bestk = k0 + j; }
            else if (dist < second) { second = dist; }
        }
    }
    if (second - best < TIE_TH) {
        double bestd = 1e300;
        int bkk = 0;
        for (int k = 0; k < KCB; ++k) {
            const float* ek = et + k * DDIM;
            double s = 0.0;
            #pragma unroll
            for (int d = 0; d < DDIM; ++d) {
                double diff = (double)xr[d] - (double)ek[d];
                s += diff * diff;
            }
            if (s < bestd) { bestd = s; bkk = k; }
        }
        bestk = bkk;
    }
    float sq = 0.f;
    {
        const float4* qp = (const float4*)(et + bestk * DDIM);
        float4* op = (float4*)(out + (size_t)n * DDIM);
        #pragma unroll
        for (int d4 = 0; d4 < DDIM / 4; ++d4) {
            float4 q = qp[d4];
            op[d4] = q;
            float a = q.x - xr[4 * d4 + 0];
            float b = q.y - xr[4 * d4 + 1];
            float c = q.z - xr[4 * d4 + 2];
            float e = q.w - xr[4 * d4 + 3];
            sq += a * a + b * b + c * c + e * e;
        }
    }
    #pragma unroll
    for (int off = 32; off > 0; off >>= 1) sq += __shfl_down(sq, off);
    __shared__ float red[4];
    const int lane = threadIdx.x & 63;
    const int wid  = threadIdx.x >> 6;
    if (lane == 0) red[wid] = sq;
    __syncthreads();
    if (threadIdx.x == 0) atomicAdd(loss_accum, red[0] + red[1] + red[2] + red[3]);
}

__global__ void vq_final(const float* __restrict__ loss_accum,
                         float* __restrict__ out) {
    out[(size_t)NVEC * DDIM] = 1.25f * loss_accum[0] / 16777216.f;
}

extern "C" void kernel_launch(void* const* d_in, const int* in_sizes, int n_in,
                              void* d_out, int out_size, void* d_ws, size_t ws_size,
                              hipStream_t stream) {
    const float* x   = (const float*)d_in[0];
    const float* emb = (const float*)d_in[1];
    float* out = (float*)d_out;
    float* wsf = (float*)d_ws;

    if (ws_size >= (size_t)WS_END * 4) {
        vq_prep<<<8, 512, 0, stream>>>(emb, wsf);
        vq_main_mfma<<<NVEC / 1024, 1024, 0, stream>>>(x, wsf, out);
        // loss written by last finishing block of vq_main_mfma
    } else {
        vq_prep1<<<1, 512, 0, stream>>>(emb, wsf);
        vq_main_legacy<<<NVEC / 256, 256, 0, stream>>>(x, emb, wsf, out, wsf + WS_LOSS);
        vq_final<<<1, 1, 0, stream>>>(wsf + WS_LOSS, out);
    }
}